// Round 6
// baseline (271.514 us; speedup 1.0000x reference)
//
#include <hip/hip_runtime.h>
#include <math.h>

// Outputs are a pure function of obs's class (NC=1000 distinct values):
// per-class tables once (fp64 trunk for argmin robustness), then scatter.
//
// R6: per_class redesigned — 4 classes per block (250 blocks). Weights and
// codebook rows are loaded once per thread and reused across classes; the
// 1000x per-block weight re-read (~500 MB L2 traffic, the invariant ~65us
// across R1/R3/R5) collapses 4x. fp64 kept end-to-end on the argmin path.

typedef float f4 __attribute__((ext_vector_type(4)));

#define CPB 4   // classes per block

__device__ __forceinline__ float sigmoidf_(float x){ return 1.0f/(1.0f + expf(-x)); }

__global__ __launch_bounds__(256) void per_class_kernel(
    const float* __restrict__ embed,
    const float* __restrict__ W1, const float* __restrict__ b1,
    const float* __restrict__ W2, const float* __restrict__ b2,
    const float* __restrict__ W3, const float* __restrict__ b3,
    const float* __restrict__ Wp, const float* __restrict__ bp,
    const float* __restrict__ cb,
    const float* __restrict__ Wa, const float* __restrict__ ba,
    const float* __restrict__ Ws, const float* __restrict__ bs,
    const float* __restrict__ Wc1, const float* __restrict__ bc1,
    const float* __restrict__ Wc2, const float* __restrict__ bc2,
    const float* __restrict__ Wc3, const float* __restrict__ bc3,
    const float* __restrict__ Wc4, const float* __restrict__ bc4,
    float* __restrict__ am_t, float* __restrict__ sd_t,
    float* __restrict__ cr_t, int* __restrict__ idx_t, float* __restrict__ e_t,
    float* __restrict__ loss_slot, int NC, int VQN)
{
    const int t  = threadIdx.x;      // 0..255
    const int c0 = blockIdx.x * CPB;
    const int n  = t & 127;          // output col for 128-wide layers
    const int g  = t >> 7;           // 0/1 — this thread handles classes 2g, 2g+1

    if (blockIdx.x == 0 && t == 0) *loss_slot = 0.0f;   // d_out re-poisoned each call

    __shared__ double X[CPB][128];
    __shared__ double Y[CPB][128];
    __shared__ double zp[CPB][64];
    __shared__ float  qv[CPB][64];
    __shared__ float  h1[CPB][128];
    __shared__ float  h2[CPB][128];
    __shared__ float  h3[CPB][32];
    __shared__ double wbest[4][CPB];
    __shared__ int    wbidx[4][CPB];
    __shared__ int    widx[CPB];

    // load embed rows for the block's 4 classes
    for (int e = t; e < CPB * 128; e += 256) {
        int lc = e >> 7, col = e & 127;
        int c = c0 + lc;
        X[lc][col] = (c < NC) ? (double)embed[(size_t)c * 128 + col] : 0.0;
    }
    __syncthreads();

    const int lcA = 2 * g, lcB = 2 * g + 1;

    // 128x128 fp64 layer: W element loaded once, used for 2 classes;
    // 4 independent FMA chains (2 classes x unroll 2).
#define LAYER(Xin, Wm, bias, Yout)                                         \
    {                                                                      \
        double a0 = 0.0, a1 = 0.0, b0 = 0.0, b1_ = 0.0;                    \
        for (int i = 0; i < 128; i += 2) {                                 \
            double w0 = (double)Wm[(i + 0) * 128 + n];                     \
            double w1 = (double)Wm[(i + 1) * 128 + n];                     \
            a0  = fma(Xin[lcA][i + 0], w0, a0);                            \
            a1  = fma(Xin[lcA][i + 1], w1, a1);                            \
            b0  = fma(Xin[lcB][i + 0], w0, b0);                            \
            b1_ = fma(Xin[lcB][i + 1], w1, b1_);                           \
        }                                                                  \
        double accA = (double)bias[n] + a0 + a1;                           \
        double accB = (double)bias[n] + b0 + b1_;                          \
        Yout[lcA][n] = accA > 0.0 ? accA : 0.0;                            \
        Yout[lcB][n] = accB > 0.0 ? accB : 0.0;                            \
        __syncthreads();                                                   \
    }

    LAYER(X, W1, b1, Y)
    LAYER(Y, W2, b2, X)
    LAYER(X, W3, b3, Y)
#undef LAYER

    // projection: zp[lc][j] = z3[lc] . Wp[:,j] + bp[j]; 4 lc-groups of 64 lanes
    {
        const int j = t & 63, lc = t >> 6;
        double a0 = 0.0, a1 = 0.0, a2 = 0.0, a3 = 0.0;
        for (int i = 0; i < 128; i += 4) {
            a0 = fma(Y[lc][i + 0], (double)Wp[(i + 0) * 64 + j], a0);
            a1 = fma(Y[lc][i + 1], (double)Wp[(i + 1) * 64 + j], a1);
            a2 = fma(Y[lc][i + 2], (double)Wp[(i + 2) * 64 + j], a2);
            a3 = fma(Y[lc][i + 3], (double)Wp[(i + 3) * 64 + j], a3);
        }
        zp[lc][j] = (double)bp[j] + (a0 + a1) + (a2 + a3);
    }
    __syncthreads();

    // VQ: thread owns codes k = t, t+256, ...; each codebook row is loaded
    // once and scored against ALL 4 classes (4 independent fp64 chains).
    double best[CPB] = {1e300, 1e300, 1e300, 1e300};
    int    bidx[CPB] = {0, 0, 0, 0};
    for (int k = t; k < VQN; k += 256) {
        const f4* crow = (const f4*)(cb + (size_t)k * 64);
        double dacc[CPB] = {0.0, 0.0, 0.0, 0.0};
        for (int j4 = 0; j4 < 16; ++j4) {
            f4 cv = crow[j4];
            double c0d = (double)cv.x, c1d = (double)cv.y;
            double c2d = (double)cv.z, c3d = (double)cv.w;
            int j = j4 * 4;
#pragma unroll
            for (int lc = 0; lc < CPB; ++lc) {
                double e0 = zp[lc][j + 0] - c0d;
                double e1 = zp[lc][j + 1] - c1d;
                double e2 = zp[lc][j + 2] - c2d;
                double e3 = zp[lc][j + 3] - c3d;
                dacc[lc] = fma(e0, e0, fma(e1, e1, fma(e2, e2, fma(e3, e3, dacc[lc]))));
            }
        }
#pragma unroll
        for (int lc = 0; lc < CPB; ++lc) {
            if (dacc[lc] < best[lc]) { best[lc] = dacc[lc]; bidx[lc] = k; }
        }
    }
    // 64-lane butterfly argmin per class, then merge 4 waves via LDS
#pragma unroll
    for (int lc = 0; lc < CPB; ++lc) {
        double b = best[lc]; int bi = bidx[lc];
        for (int s = 32; s > 0; s >>= 1) {
            double ob = __shfl_down(b, s, 64);
            int    oi = __shfl_down(bi, s, 64);
            if (ob < b || (ob == b && oi < bi)) { b = ob; bi = oi; }
        }
        if ((t & 63) == 0) { wbest[t >> 6][lc] = b; wbidx[t >> 6][lc] = bi; }
    }
    __syncthreads();
    if (t < CPB) {
        double b = wbest[0][t]; int bi = wbidx[0][t];
        for (int w = 1; w < 4; ++w) {
            if (wbest[w][t] < b || (wbest[w][t] == b && wbidx[w][t] < bi)) {
                b = wbest[w][t]; bi = wbidx[w][t];
            }
        }
        widx[t] = bi;
    }
    __syncthreads();

    // gather winning code + e[lc] = |q - z|^2 (fp64, 64-lane wave reduce)
    {
        const int j = t & 63, lc = t >> 6;      // lc constant within a wave
        float q = cb[(size_t)widx[lc] * 64 + j];
        qv[lc][j] = q;
        double d = (double)q - zp[lc][j];
        double s = d * d;
        for (int sh = 32; sh > 0; sh >>= 1) s += __shfl_down(s, sh, 64);
        if (j == 0 && (c0 + lc) < NC) e_t[c0 + lc] = (float)s;
    }
    __syncthreads();

    // heads (fp32): Wa/Ws/Wc1 element loaded once, used for 2 classes
    {
        float laA = ba[n],  laB = ba[n];
        float lsA = bs[n],  lsB = bs[n];
        float l1A = bc1[n], l1B = bc1[n];
        for (int j = 0; j < 64; ++j) {
            float wa = Wa[j * 128 + n], ws = Ws[j * 128 + n], w1 = Wc1[j * 128 + n];
            float qA = qv[lcA][j], qB = qv[lcB][j];
            laA = fmaf(qA, wa, laA); laB = fmaf(qB, wa, laB);
            lsA = fmaf(qA, ws, lsA); lsB = fmaf(qB, ws, lsB);
            l1A = fmaf(qA, w1, l1A); l1B = fmaf(qB, w1, l1B);
        }
        int cA = c0 + lcA, cB = c0 + lcB;
        if (cA < NC) {
            am_t[(size_t)cA * 128 + n] = sigmoidf_(laA);
            sd_t[(size_t)cA * 128 + n] = sigmoidf_(lsA) * 1.0f + 1e-8f;  // SQUISH=1
        }
        if (cB < NC) {
            am_t[(size_t)cB * 128 + n] = sigmoidf_(laB);
            sd_t[(size_t)cB * 128 + n] = sigmoidf_(lsB) * 1.0f + 1e-8f;
        }
        h1[lcA][n] = sigmoidf_(l1A);
        h1[lcB][n] = sigmoidf_(l1B);
    }
    __syncthreads();

    // critic layer 2 (128->128)
    {
        float aA = bc2[n], a2A = 0.0f, aB = bc2[n], a2B = 0.0f;
        for (int i = 0; i < 128; i += 2) {
            float w0 = Wc2[(i + 0) * 128 + n], w1 = Wc2[(i + 1) * 128 + n];
            aA  = fmaf(h1[lcA][i + 0], w0, aA);
            a2A = fmaf(h1[lcA][i + 1], w1, a2A);
            aB  = fmaf(h1[lcB][i + 0], w0, aB);
            a2B = fmaf(h1[lcB][i + 1], w1, a2B);
        }
        h2[lcA][n] = sigmoidf_(aA + a2A);
        h2[lcB][n] = sigmoidf_(aB + a2B);
    }
    __syncthreads();

    // critic layer 3 (128->32): 4 classes x 32 outputs = 128 threads
    if (t < 128) {
        int lc = t >> 5, m = t & 31;
        float a0 = bc3[m], a1 = 0.0f;
        for (int i = 0; i < 128; i += 2) {
            a0 = fmaf(h2[lc][i + 0], Wc3[(i + 0) * 32 + m], a0);
            a1 = fmaf(h2[lc][i + 1], Wc3[(i + 1) * 32 + m], a1);
        }
        h3[lc][m] = sigmoidf_(a0 + a1);
    }
    __syncthreads();

    // critic tail (32->1, no sigmoid) + idx
    if (t < CPB) {
        float a = bc4[0];
        for (int i = 0; i < 32; ++i) a = fmaf(h3[t][i], Wc4[i], a);
        int c = c0 + t;
        if (c < NC) { cr_t[c] = a; idx_t[c] = widx[t]; }
    }
}

// am/sd/critic/idx scatter: one float4 per thread, coalesced nontemporal
// writes, NO barrier, NO atomic (R4 lesson: 16k same-address atomics = 216us).
__global__ __launch_bounds__(256) void scatter_vec_kernel(
    const int* __restrict__ obs,
    const f4* __restrict__ am_t, const f4* __restrict__ sd_t,
    const float* __restrict__ cr_t, const int* __restrict__ idx_t,
    f4* __restrict__ out_am, f4* __restrict__ out_sd,
    float* __restrict__ out_critic, float* __restrict__ out_idx, int B)
{
    int gid = blockIdx.x * 256 + threadIdx.x;
    int half = B * 32;                       // B*128/4
    if (gid < half) {
        int b = gid >> 5;
        int j = gid & 31;
        int o = obs[b];
        __builtin_nontemporal_store(am_t[(size_t)o * 32 + j], &out_am[gid]);
        if (j == 0) __builtin_nontemporal_store(cr_t[o], &out_critic[b]);
    } else {
        int g = gid - half;
        int b = g >> 5;
        int j = g & 31;
        int o = obs[b];
        __builtin_nontemporal_store(sd_t[(size_t)o * 32 + j], &out_sd[g]);
        if (j == 0) __builtin_nontemporal_store((float)idx_t[o], &out_idx[b]);
    }
}

// vq_loss: 1024-thread blocks, shfl+LDS reduce, ONE atomic per block (128 total)
__global__ __launch_bounds__(1024) void loss_kernel(
    const int* __restrict__ obs, const float* __restrict__ e_t,
    float* __restrict__ out_loss, int B, float scale)
{
    int i = blockIdx.x * 1024 + threadIdx.x;
    float e = (i < B) ? e_t[obs[i]] : 0.0f;
    for (int s = 32; s > 0; s >>= 1) e += __shfl_down(e, s, 64);
    __shared__ float w[16];
    int lane = threadIdx.x & 63, wid = threadIdx.x >> 6;
    if (lane == 0) w[wid] = e;
    __syncthreads();
    if (threadIdx.x == 0) {
        float s = 0.0f;
        for (int k = 0; k < 16; ++k) s += w[k];
        atomicAdd(out_loss, s * scale);
    }
}

extern "C" void kernel_launch(void* const* d_in, const int* in_sizes, int n_in,
                              void* d_out, int out_size, void* d_ws, size_t ws_size,
                              hipStream_t stream)
{
    const int*   obs   = (const int*)  d_in[0];
    const float* embed = (const float*)d_in[1];
    const float* W1    = (const float*)d_in[2];
    const float* b1    = (const float*)d_in[3];
    const float* W2    = (const float*)d_in[4];
    const float* b2    = (const float*)d_in[5];
    const float* W3    = (const float*)d_in[6];
    const float* b3    = (const float*)d_in[7];
    const float* Wp    = (const float*)d_in[8];
    const float* bp    = (const float*)d_in[9];
    const float* cb    = (const float*)d_in[10];
    const float* Wa    = (const float*)d_in[11];
    const float* ba    = (const float*)d_in[12];
    const float* Ws    = (const float*)d_in[13];
    const float* bs    = (const float*)d_in[14];
    const float* Wc1   = (const float*)d_in[15];
    const float* bc1   = (const float*)d_in[16];
    const float* Wc2   = (const float*)d_in[17];
    const float* bc2   = (const float*)d_in[18];
    const float* Wc3   = (const float*)d_in[19];
    const float* bc3   = (const float*)d_in[20];
    const float* Wc4   = (const float*)d_in[21];
    const float* bc4   = (const float*)d_in[22];

    const int B   = in_sizes[0];
    const int NC  = in_sizes[1] / 128;
    const int VQN = in_sizes[10] / 64;

    // workspace tables (~1.04 MB for NC=1000)
    float* am_t = (float*)d_ws;
    float* sd_t = am_t + (size_t)NC * 128;
    float* cr_t = sd_t + (size_t)NC * 128;
    float* e_t  = cr_t + NC;
    int*   idx_t = (int*)(e_t + NC);

    float* out = (float*)d_out;
    const size_t sd_off   = (size_t)B * 128;
    const size_t cr_off   = (size_t)B * 256;     // after am + sd
    const size_t loss_off = cr_off + (size_t)B;
    const size_t idx_off  = loss_off + 1;

    per_class_kernel<<<(NC + CPB - 1) / CPB, 256, 0, stream>>>(
        embed, W1, b1, W2, b2, W3, b3, Wp, bp, cb,
        Wa, ba, Ws, bs, Wc1, bc1, Wc2, bc2, Wc3, bc3, Wc4, bc4,
        am_t, sd_t, cr_t, idx_t, e_t, out + loss_off, NC, VQN);

    int vec_threads = 2 * B * 32;                // 2 * B * 128 / 4 float4s
    scatter_vec_kernel<<<vec_threads / 256, 256, 0, stream>>>(
        obs, (const f4*)am_t, (const f4*)sd_t, cr_t, idx_t,
        (f4*)out, (f4*)(out + sd_off),
        out + cr_off, out + idx_off, B);

    loss_kernel<<<(B + 1023) / 1024, 1024, 0, stream>>>(
        obs, e_t, out + loss_off, B, 1.25f / ((float)B * 64.0f));
}

// Round 7
// 255.892 us; speedup vs baseline: 1.0610x; 1.0610x over previous
//
#include <hip/hip_runtime.h>
#include <math.h>

// Outputs are a pure function of obs's class (NC=1000 distinct values):
// per-class tables once (fp64 trunk for argmin robustness), then scatter.
//
// R7: revert per_class to the R3 variant (best measured: 255.4us total;
// R5 split-K +9us, R6 CPB=4 +16us — per_class is ~8-10us and latency-
// cheap, the restructures only added barriers / cut occupancy).
// Scatter: am+sd fused per thread (one obs read, two nt stores), NO
// barrier, NO atomic (R4: 16k same-address atomics = +216us). Loss in a
// separate 128-block kernel.

typedef float f4 __attribute__((ext_vector_type(4)));

__device__ __forceinline__ float sigmoidf_(float x){ return 1.0f/(1.0f + expf(-x)); }

__global__ __launch_bounds__(128) void per_class_kernel(
    const float* __restrict__ embed,
    const float* __restrict__ W1, const float* __restrict__ b1,
    const float* __restrict__ W2, const float* __restrict__ b2,
    const float* __restrict__ W3, const float* __restrict__ b3,
    const float* __restrict__ Wp, const float* __restrict__ bp,
    const float* __restrict__ cb,
    const float* __restrict__ Wa, const float* __restrict__ ba,
    const float* __restrict__ Ws, const float* __restrict__ bs,
    const float* __restrict__ Wc1, const float* __restrict__ bc1,
    const float* __restrict__ Wc2, const float* __restrict__ bc2,
    const float* __restrict__ Wc3, const float* __restrict__ bc3,
    const float* __restrict__ Wc4, const float* __restrict__ bc4,
    float* __restrict__ am_t, float* __restrict__ sd_t,
    float* __restrict__ cr_t, int* __restrict__ idx_t, float* __restrict__ e_t,
    float* __restrict__ loss_slot, int VQN)
{
    const int c = blockIdx.x;
    const int t = threadIdx.x;     // 0..127
    if (c == 0 && t == 0) *loss_slot = 0.0f;   // d_out is poisoned each call

    __shared__ double Abuf[128];
    __shared__ double Bbuf[128];
    __shared__ double zp[64];
    __shared__ float  qv[64];
    __shared__ double rd[128];
    __shared__ int    ri[128];
    __shared__ float  h1[128], h2[128], h3[32];

    // y = embed[c]
    Abuf[t] = (double)embed[(size_t)c * 128 + t];
    __syncthreads();

    // z1 = relu(y @ W1 + b1) — 4 independent accumulators (chain len 32)
    {
        double a0 = (double)b1[t], a1 = 0.0, a2 = 0.0, a3 = 0.0;
        for (int i = 0; i < 128; i += 4) {
            a0 = fma(Abuf[i+0], (double)W1[(i+0) * 128 + t], a0);
            a1 = fma(Abuf[i+1], (double)W1[(i+1) * 128 + t], a1);
            a2 = fma(Abuf[i+2], (double)W1[(i+2) * 128 + t], a2);
            a3 = fma(Abuf[i+3], (double)W1[(i+3) * 128 + t], a3);
        }
        double acc = (a0 + a1) + (a2 + a3);
        Bbuf[t] = acc > 0.0 ? acc : 0.0;
    }
    __syncthreads();

    // z2 = relu(z1 @ W2 + b2)
    {
        double a0 = (double)b2[t], a1 = 0.0, a2 = 0.0, a3 = 0.0;
        for (int i = 0; i < 128; i += 4) {
            a0 = fma(Bbuf[i+0], (double)W2[(i+0) * 128 + t], a0);
            a1 = fma(Bbuf[i+1], (double)W2[(i+1) * 128 + t], a1);
            a2 = fma(Bbuf[i+2], (double)W2[(i+2) * 128 + t], a2);
            a3 = fma(Bbuf[i+3], (double)W2[(i+3) * 128 + t], a3);
        }
        double acc = (a0 + a1) + (a2 + a3);
        Abuf[t] = acc > 0.0 ? acc : 0.0;
    }
    __syncthreads();

    // z3 = relu(z2 @ W3 + b3)
    {
        double a0 = (double)b3[t], a1 = 0.0, a2 = 0.0, a3 = 0.0;
        for (int i = 0; i < 128; i += 4) {
            a0 = fma(Abuf[i+0], (double)W3[(i+0) * 128 + t], a0);
            a1 = fma(Abuf[i+1], (double)W3[(i+1) * 128 + t], a1);
            a2 = fma(Abuf[i+2], (double)W3[(i+2) * 128 + t], a2);
            a3 = fma(Abuf[i+3], (double)W3[(i+3) * 128 + t], a3);
        }
        double acc = (a0 + a1) + (a2 + a3);
        Bbuf[t] = acc > 0.0 ? acc : 0.0;
    }
    __syncthreads();

    // zp = z3 @ Wp + bp   (64 outputs)
    if (t < 64) {
        double a0 = (double)bp[t], a1 = 0.0, a2 = 0.0, a3 = 0.0;
        for (int i = 0; i < 128; i += 4) {
            a0 = fma(Bbuf[i+0], (double)Wp[(i+0) * 64 + t], a0);
            a1 = fma(Bbuf[i+1], (double)Wp[(i+1) * 64 + t], a1);
            a2 = fma(Bbuf[i+2], (double)Wp[(i+2) * 64 + t], a2);
            a3 = fma(Bbuf[i+3], (double)Wp[(i+3) * 64 + t], a3);
        }
        zp[t] = (a0 + a1) + (a2 + a3);
    }
    __syncthreads();

    // VQ argmin over VQN codes; thread t owns codes t, t+128, ...
    double best = 1e300; int bidx = 0;
    for (int k = t; k < VQN; k += 128) {
        const float* crow = cb + (size_t)k * 64;
        double s0 = 0.0, s1 = 0.0;
        for (int j = 0; j < 64; j += 2) {
            double d0 = zp[j+0] - (double)crow[j+0];
            double d1 = zp[j+1] - (double)crow[j+1];
            s0 = fma(d0, d0, s0);
            s1 = fma(d1, d1, s1);
        }
        double s = s0 + s1;
        if (s < best) { best = s; bidx = k; }
    }
    rd[t] = best; ri[t] = bidx;
    __syncthreads();
    for (int sft = 64; sft > 0; sft >>= 1) {
        if (t < sft) {
            if (rd[t + sft] < rd[t] || (rd[t + sft] == rd[t] && ri[t + sft] < ri[t])) {
                rd[t] = rd[t + sft]; ri[t] = ri[t + sft];
            }
        }
        __syncthreads();
    }
    const int widx = ri[0];
    if (t < 64) qv[t] = cb[(size_t)widx * 64 + t];
    __syncthreads();

    // heads (fp32; q = exact codebook row, tolerance is ~2% of max)
    {
        float la0 = ba[t],  la1 = 0.0f;
        float ls0 = bs[t],  ls1 = 0.0f;
        float l10 = bc1[t], l11 = 0.0f;
        for (int j = 0; j < 64; j += 2) {
            float q0 = qv[j], q1 = qv[j+1];
            la0 = fmaf(q0, Wa[j * 128 + t], la0);
            la1 = fmaf(q1, Wa[(j+1) * 128 + t], la1);
            ls0 = fmaf(q0, Ws[j * 128 + t], ls0);
            ls1 = fmaf(q1, Ws[(j+1) * 128 + t], ls1);
            l10 = fmaf(q0, Wc1[j * 128 + t], l10);
            l11 = fmaf(q1, Wc1[(j+1) * 128 + t], l11);
        }
        am_t[(size_t)c * 128 + t] = sigmoidf_(la0 + la1);
        sd_t[(size_t)c * 128 + t] = sigmoidf_(ls0 + ls1) * 1.0f + 1e-8f;   // SQUISH=1.0
        h1[t] = sigmoidf_(l10 + l11);
    }
    __syncthreads();

    {
        float l20 = bc2[t], l21 = 0.0f;
        for (int i = 0; i < 128; i += 2) {
            l20 = fmaf(h1[i],   Wc2[i * 128 + t],     l20);
            l21 = fmaf(h1[i+1], Wc2[(i+1) * 128 + t], l21);
        }
        h2[t] = sigmoidf_(l20 + l21);
    }
    __syncthreads();

    if (t < 32) {
        float l30 = bc3[t], l31 = 0.0f;
        for (int i = 0; i < 128; i += 2) {
            l30 = fmaf(h2[i],   Wc3[i * 32 + t],     l30);
            l31 = fmaf(h2[i+1], Wc3[(i+1) * 32 + t], l31);
        }
        h3[t] = sigmoidf_(l30 + l31);
    }
    __syncthreads();

    if (t == 0) {
        float l4 = bc4[0];
        for (int i = 0; i < 32; ++i) l4 = fmaf(h3[i], Wc4[i], l4);
        cr_t[c] = l4;              // no sigmoid on final critic layer
        idx_t[c] = widx;
        double e0 = 0.0, e1 = 0.0;
        for (int j = 0; j < 64; j += 2) {
            double d0 = (double)qv[j]   - zp[j];
            double d1 = (double)qv[j+1] - zp[j+1];
            e0 = fma(d0, d0, e0); e1 = fma(d1, d1, e1);
        }
        e_t[c] = (float)(e0 + e1); // sum over 64 dims of (quant-z)^2
    }
}

// Fused scatter: thread (b,j) reads obs once, writes am+sd float4s; j==0
// lane also writes critic/idx. NO barrier, NO atomic.
__global__ __launch_bounds__(256) void scatter_vec_kernel(
    const int* __restrict__ obs,
    const f4* __restrict__ am_t, const f4* __restrict__ sd_t,
    const float* __restrict__ cr_t, const int* __restrict__ idx_t,
    f4* __restrict__ out_am, f4* __restrict__ out_sd,
    float* __restrict__ out_critic, float* __restrict__ out_idx)
{
    int gid = blockIdx.x * 256 + threadIdx.x;    // [0, B*32)
    int b = gid >> 5;                            // 32 float4 per row
    int j = gid & 31;
    int o = obs[b];
    __builtin_nontemporal_store(am_t[(size_t)o * 32 + j], &out_am[gid]);
    __builtin_nontemporal_store(sd_t[(size_t)o * 32 + j], &out_sd[gid]);
    if (j == 0) {
        __builtin_nontemporal_store(cr_t[o], &out_critic[b]);
        __builtin_nontemporal_store((float)idx_t[o], &out_idx[b]);
    }
}

// vq_loss: 1024-thread blocks, shfl+LDS reduce, ONE atomic per block (128 total)
__global__ __launch_bounds__(1024) void loss_kernel(
    const int* __restrict__ obs, const float* __restrict__ e_t,
    float* __restrict__ out_loss, int B, float scale)
{
    int i = blockIdx.x * 1024 + threadIdx.x;
    float e = (i < B) ? e_t[obs[i]] : 0.0f;
    for (int s = 32; s > 0; s >>= 1) e += __shfl_down(e, s, 64);
    __shared__ float w[16];
    int lane = threadIdx.x & 63, wid = threadIdx.x >> 6;
    if (lane == 0) w[wid] = e;
    __syncthreads();
    if (threadIdx.x == 0) {
        float s = 0.0f;
        for (int k = 0; k < 16; ++k) s += w[k];
        atomicAdd(out_loss, s * scale);
    }
}

extern "C" void kernel_launch(void* const* d_in, const int* in_sizes, int n_in,
                              void* d_out, int out_size, void* d_ws, size_t ws_size,
                              hipStream_t stream)
{
    const int*   obs   = (const int*)  d_in[0];
    const float* embed = (const float*)d_in[1];
    const float* W1    = (const float*)d_in[2];
    const float* b1    = (const float*)d_in[3];
    const float* W2    = (const float*)d_in[4];
    const float* b2    = (const float*)d_in[5];
    const float* W3    = (const float*)d_in[6];
    const float* b3    = (const float*)d_in[7];
    const float* Wp    = (const float*)d_in[8];
    const float* bp    = (const float*)d_in[9];
    const float* cb    = (const float*)d_in[10];
    const float* Wa    = (const float*)d_in[11];
    const float* ba    = (const float*)d_in[12];
    const float* Ws    = (const float*)d_in[13];
    const float* bs    = (const float*)d_in[14];
    const float* Wc1   = (const float*)d_in[15];
    const float* bc1   = (const float*)d_in[16];
    const float* Wc2   = (const float*)d_in[17];
    const float* bc2   = (const float*)d_in[18];
    const float* Wc3   = (const float*)d_in[19];
    const float* bc3   = (const float*)d_in[20];
    const float* Wc4   = (const float*)d_in[21];
    const float* bc4   = (const float*)d_in[22];

    const int B   = in_sizes[0];
    const int NC  = in_sizes[1] / 128;
    const int VQN = in_sizes[10] / 64;

    // workspace tables (~1.04 MB for NC=1000)
    float* am_t = (float*)d_ws;
    float* sd_t = am_t + (size_t)NC * 128;
    float* cr_t = sd_t + (size_t)NC * 128;
    float* e_t  = cr_t + NC;
    int*   idx_t = (int*)(e_t + NC);

    float* out = (float*)d_out;
    const size_t sd_off   = (size_t)B * 128;
    const size_t cr_off   = (size_t)B * 256;     // after am + sd
    const size_t loss_off = cr_off + (size_t)B;
    const size_t idx_off  = loss_off + 1;

    per_class_kernel<<<NC, 128, 0, stream>>>(
        embed, W1, b1, W2, b2, W3, b3, Wp, bp, cb,
        Wa, ba, Ws, bs, Wc1, bc1, Wc2, bc2, Wc3, bc3, Wc4, bc4,
        am_t, sd_t, cr_t, idx_t, e_t, out + loss_off, VQN);

    int nthreads = B * 32;                       // one float4-pair per thread
    scatter_vec_kernel<<<nthreads / 256, 256, 0, stream>>>(
        obs, (const f4*)am_t, (const f4*)sd_t, cr_t, idx_t,
        (f4*)out, (f4*)(out + sd_off),
        out + cr_off, out + idx_off);

    loss_kernel<<<(B + 1023) / 1024, 1024, 0, stream>>>(
        obs, e_t, out + loss_off, B, 1.25f / ((float)B * 64.0f));
}